// Round 1
// baseline (10091.761 us; speedup 1.0000x reference)
//
#include <hip/hip_runtime.h>

#define NTOT  10000
#define TALL  64
#define TCTX  24
#define HOR   40
#define HH    128
#define G4    512
#define NENV  17
#define SAMP  16
#define MPAD  24

// ws layout (floats)
#define OFF_M0  0
#define OFF_MD  (G4*MPAD)
#define OFF_W1I (2*G4*MPAD)
#define OFF_W1H (2*G4*MPAD + HH*MPAD)

__device__ __forceinline__ float sigf(float v)   { return 1.0f/(1.0f + __expf(-v)); }
__device__ __forceinline__ float tanhf_(float v) { return 1.0f - 2.0f/(__expf(2.0f*v) + 1.0f); }

// ---- precompute: fold input-projection chains into 512x21 matrices ----
// dest col layout per row (MPAD=24): [0..16]=env coefs, [17]=x coef, [18,19]=coords, [20]=areas, [21..23]=0
__global__ void fold_kernel(const float* __restrict__ enc_Wih,
                            const float* __restrict__ W_enc_in,
                            const float* __restrict__ in_Wih,
                            const float* __restrict__ W_dec_in,
                            const float* __restrict__ mlp_W1,
                            float* __restrict__ ws)
{
    int j = blockIdx.x*256 + threadIdx.x;
    if (j >= 2*G4 + HH) return;
    float vals[21];
    float* dst;
    if (j < 2*G4) {
        const float* A = (j < G4) ? (enc_Wih + j*HH) : (in_Wih + (size_t)(j-G4)*2*HH);
        const float* B = (j < G4) ? W_enc_in : W_dec_in;
        for (int c = 0; c < 21; ++c) {
            float a = 0.f;
            for (int k = 0; k < HH; ++k) a = fmaf(A[k], B[k*21 + c], a);
            vals[c] = a;
        }
        dst = ws + ((j < G4) ? (OFF_M0 + j*MPAD) : (OFF_MD + (j-G4)*MPAD));
    } else {
        int u = j - 2*G4;
        for (int c = 0; c < 21; ++c) vals[c] = mlp_W1[u*149 + HH + c];
        dst = ws + OFF_W1I + u*MPAD;
    }
    for (int e = 0; e < 17; ++e) dst[e] = vals[3+e];
    dst[17] = vals[0];
    dst[18] = vals[1];
    dst[19] = vals[2];
    dst[20] = vals[20];
    dst[21] = 0.f; dst[22] = 0.f; dst[23] = 0.f;
}

// repack mlp_W1[:, :128] to aligned 128x128 (row stride 149 is not 16B-aligned)
__global__ void copyw1h_kernel(const float* __restrict__ mlp_W1, float* __restrict__ ws)
{
    int i = blockIdx.x*256 + threadIdx.x;
    if (i < HH*HH) ws[OFF_W1H + i] = mlp_W1[(i >> 7)*149 + (i & 127)];
}

// ---- main persistent kernel ----

__device__ __forceinline__ void mm_acc(float acc[8][4], const float* __restrict__ WB,
                                       int wstride, const float (*HS)[132],
                                       const int* rows, int slb)
{
#pragma unroll 2
    for (int k4 = 0; k4 < 32; ++k4) {
        float4 hv[4];
#pragma unroll
        for (int q = 0; q < 4; ++q)
            hv[q] = *(const float4*)(&HS[slb+q][k4*4]);
#pragma unroll
        for (int jj = 0; jj < 8; ++jj) {
            float4 w = *(const float4*)(WB + rows[jj]*wstride + k4*4);
#pragma unroll
            for (int q = 0; q < 4; ++q)
                acc[jj][q] = fmaf(w.x, hv[q].x, fmaf(w.y, hv[q].y,
                             fmaf(w.z, hv[q].z, fmaf(w.w, hv[q].w, acc[jj][q]))));
        }
    }
}

__device__ __forceinline__ void envx_add(float acc[8][4], const float* __restrict__ MB,
                                         const int* rows, int slb, const float (*envs)[20],
                                         const float* xv)
{
#pragma unroll
    for (int e4 = 0; e4 < 4; ++e4) {
        float4 ev[4];
#pragma unroll
        for (int q = 0; q < 4; ++q)
            ev[q] = *(const float4*)(&envs[slb+q][e4*4]);
#pragma unroll
        for (int jj = 0; jj < 8; ++jj) {
            float4 m4 = *(const float4*)(MB + rows[jj]*MPAD + e4*4);
#pragma unroll
            for (int q = 0; q < 4; ++q)
                acc[jj][q] = fmaf(m4.x, ev[q].x, fmaf(m4.y, ev[q].y,
                             fmaf(m4.z, ev[q].z, fmaf(m4.w, ev[q].w, acc[jj][q]))));
        }
    }
    float e16[4];
#pragma unroll
    for (int q = 0; q < 4; ++q) e16[q] = envs[slb+q][16];
#pragma unroll
    for (int jj = 0; jj < 8; ++jj) {
        float m16 = MB[rows[jj]*MPAD + 16];
        float m17 = MB[rows[jj]*MPAD + 17];
#pragma unroll
        for (int q = 0; q < 4; ++q)
            acc[jj][q] = fmaf(m16, e16[q], fmaf(m17, xv[q], acc[jj][q]));
    }
}

__device__ __forceinline__ void cell_upd(float acc[8][4], float cr[2][4], float h2[2][4])
{
#pragma unroll
    for (int uu = 0; uu < 2; ++uu)
#pragma unroll
        for (int q = 0; q < 4; ++q) {
            float gi = acc[uu*4+0][q], gf = acc[uu*4+1][q];
            float gg = acc[uu*4+2][q], go = acc[uu*4+3][q];
            float c2 = fmaf(sigf(gf), cr[uu][q], sigf(gi)*tanhf_(gg));
            cr[uu][q] = c2;
            h2[uu][q] = sigf(go)*tanhf_(c2);
        }
}

__global__ __launch_bounds__(256, 2)
void lstm_main(const float* __restrict__ x, const float* __restrict__ coords,
               const float* __restrict__ env, const float* __restrict__ areas,
               const float* __restrict__ enc_Wih, const float* __restrict__ enc_Whh,
               const float* __restrict__ enc_bih, const float* __restrict__ enc_bhh,
               const float* __restrict__ in_Wih, const float* __restrict__ in_Whh,
               const float* __restrict__ in_bih, const float* __restrict__ in_bhh,
               const float* __restrict__ dWih, const float* __restrict__ dWhh,
               const float* __restrict__ dbih, const float* __restrict__ dbhh,
               const float* __restrict__ mlp_b1, const float* __restrict__ mlp_W2,
               const float* __restrict__ mlp_b2, const float* __restrict__ ws,
               float* __restrict__ out)
{
    __shared__ float h0s[SAMP][132];
    __shared__ float h1s[SAMP][132];
    __shared__ float zms[SAMP][132];
    __shared__ float envs[SAMP][20];
    __shared__ float xcs[SAMP];

    const int tid = threadIdx.x;
    const int jg  = tid >> 2;     // 0..63 -> owns units 2*jg, 2*jg+1
    const int sg  = tid & 3;      // 0..3  -> owns local samples sg*4 .. sg*4+3
    const int u0  = jg * 2;
    const int slb = sg * 4;
    const int s0  = blockIdx.x * SAMP;

    int rows[8];
#pragma unroll
    for (int uu = 0; uu < 2; ++uu)
#pragma unroll
        for (int g = 0; g < 4; ++g)
            rows[uu*4+g] = (u0+uu) + g*HH;

    // env staging map (272 elements over 256 threads; tid<16 do a second one)
    const int sa = tid / NENV, ea = tid - sa*NENV;
    const int ib = tid + 256;
    const int sb = ib / NENV, eb = ib - sb*NENV;
    const float* envpA = env + ((size_t)(s0+sa)*NENV + ea)*TALL;
    const float* envpB = env + ((size_t)(s0 + ((tid<16)?sb:0))*NENV + ((tid<16)?eb:0))*TALL;
    const float* xrow  = x + (size_t)(s0 + (tid & (SAMP-1)))*TALL;

    const float* M0  = ws + OFF_M0;
    const float* Md  = ws + OFF_MD;
    const float* W1i = ws + OFF_W1I;
    const float* W1h = ws + OFF_W1H;

    // per-sample constants
    float cd0[4], cd1[4], ar[4];
#pragma unroll
    for (int q = 0; q < 4; ++q) {
        int s = s0 + slb + q;
        cd0[q] = coords[s*2+0];
        cd1[q] = coords[s*2+1];
        ar[q]  = areas[s];
    }

    // encoder layer0 gate base (coords/areas/bias folded), layer1 bias
    float base[8][4], lb1[8];
#pragma unroll
    for (int jj = 0; jj < 8; ++jj) {
        int r = rows[jj];
        const float* m = M0 + r*MPAD;
        float bb = enc_bih[r] + enc_bhh[r];
        float m18 = m[18], m19 = m[19], m20 = m[20];
#pragma unroll
        for (int q = 0; q < 4; ++q)
            base[jj][q] = fmaf(cd0[q], m18, fmaf(cd1[q], m19, fmaf(ar[q], m20, bb)));
        lb1[jj] = enc_bih[G4 + r] + enc_bhh[G4 + r];
    }

    float c0r[2][4] = {{0.f,0.f,0.f,0.f},{0.f,0.f,0.f,0.f}};
    float c1r[2][4] = {{0.f,0.f,0.f,0.f},{0.f,0.f,0.f,0.f}};
#pragma unroll
    for (int uu = 0; uu < 2; ++uu)
#pragma unroll
        for (int q = 0; q < 4; ++q) {
            h0s[slb+q][u0+uu] = 0.f;
            h1s[slb+q][u0+uu] = 0.f;
        }
    __syncthreads();

    const float* Wih1 = enc_Wih + G4*HH;
    const float* Whh1 = enc_Whh + G4*HH;

    // ================= encoder =================
#pragma unroll 1
    for (int t = 0; t < TCTX; ++t) {
        (&envs[0][0])[sa*20+ea] = envpA[t];
        if (tid < 16) { (&envs[0][0])[sb*20+eb] = envpB[t]; xcs[tid] = xrow[t]; }
        __syncthreads();

        float xv[4];
#pragma unroll
        for (int q = 0; q < 4; ++q) xv[q] = xcs[slb+q];

        float acc[8][4];
#pragma unroll
        for (int jj = 0; jj < 8; ++jj)
#pragma unroll
            for (int q = 0; q < 4; ++q) acc[jj][q] = base[jj][q];

        envx_add(acc, M0, rows, slb, envs, xv);
        mm_acc(acc, enc_Whh, HH, h0s, rows, slb);     // layer0: + h0 @ Whh0^T

        float h2[2][4];
        cell_upd(acc, c0r, h2);
        __syncthreads();
#pragma unroll
        for (int uu = 0; uu < 2; ++uu)
#pragma unroll
            for (int q = 0; q < 4; ++q) h0s[slb+q][u0+uu] = h2[uu][q];
        __syncthreads();

#pragma unroll
        for (int jj = 0; jj < 8; ++jj)
#pragma unroll
            for (int q = 0; q < 4; ++q) acc[jj][q] = lb1[jj];
        mm_acc(acc, Wih1, HH, h0s, rows, slb);        // layer1: h0_new @ Wih1^T
        mm_acc(acc, Whh1, HH, h1s, rows, slb);        //         + h1 @ Whh1^T
        cell_upd(acc, c1r, h2);
        __syncthreads();
#pragma unroll
        for (int uu = 0; uu < 2; ++uu)
#pragma unroll
            for (int q = 0; q < 4; ++q) h1s[slb+q][u0+uu] = h2[uu][q];
        // next-iteration top __syncthreads covers the WAR/RAW on h1s/envs
    }

    __syncthreads();  // enc_state (h1s) fully written before folding it

    // ================= decoder init =================
    // base := coords/areas/bias + enc_state @ in_Wih[:, H:]^T  (constant over horizon)
#pragma unroll
    for (int jj = 0; jj < 8; ++jj) {
        int r = rows[jj];
        const float* m = Md + r*MPAD;
        float bb = in_bih[r] + in_bhh[r];
        float m18 = m[18], m19 = m[19], m20 = m[20];
#pragma unroll
        for (int q = 0; q < 4; ++q)
            base[jj][q] = fmaf(cd0[q], m18, fmaf(cd1[q], m19, fmaf(ar[q], m20, bb)));
        lb1[jj] = dbih[r] + dbhh[r];
    }
#pragma unroll 2
    for (int k4 = 0; k4 < 32; ++k4) {
        float4 hv[4];
#pragma unroll
        for (int q = 0; q < 4; ++q) hv[q] = *(const float4*)(&h1s[slb+q][k4*4]);
#pragma unroll
        for (int jj = 0; jj < 8; ++jj) {
            float4 w = *(const float4*)(in_Wih + (size_t)rows[jj]*(2*HH) + HH + k4*4);
#pragma unroll
            for (int q = 0; q < 4; ++q)
                base[jj][q] = fmaf(w.x, hv[q].x, fmaf(w.y, hv[q].y,
                              fmaf(w.z, hv[q].z, fmaf(w.w, hv[q].w, base[jj][q]))));
        }
    }
    float mb[2][4];
#pragma unroll
    for (int uu = 0; uu < 2; ++uu) {
        const float* m = W1i + (u0+uu)*MPAD;
        float bm = mlp_b1[u0+uu];
        float m18 = m[18], m19 = m[19], m20 = m[20];
#pragma unroll
        for (int q = 0; q < 4; ++q)
            mb[uu][q] = fmaf(cd0[q], m18, fmaf(cd1[q], m19, fmaf(ar[q], m20, bm)));
    }
    if (tid < SAMP) xcs[tid] = xrow[TCTX-1];
    __syncthreads();

    // ================= decoder =================
#pragma unroll 1
    for (int td = 0; td < HOR; ++td) {
        const int t = TCTX + td;
        (&envs[0][0])[sa*20+ea] = envpA[t];
        if (tid < 16) (&envs[0][0])[sb*20+eb] = envpB[t];
        __syncthreads();

        float xv[4];
#pragma unroll
        for (int q = 0; q < 4; ++q) xv[q] = xcs[slb+q];

        float acc[8][4];
#pragma unroll
        for (int jj = 0; jj < 8; ++jj)
#pragma unroll
            for (int q = 0; q < 4; ++q) acc[jj][q] = base[jj][q];

        envx_add(acc, Md, rows, slb, envs, xv);
        mm_acc(acc, in_Whh, HH, h0s, rows, slb);

        float h2[2][4];
        cell_upd(acc, c0r, h2);
        __syncthreads();
#pragma unroll
        for (int uu = 0; uu < 2; ++uu)
#pragma unroll
            for (int q = 0; q < 4; ++q) h0s[slb+q][u0+uu] = h2[uu][q];
        __syncthreads();

#pragma unroll
        for (int jj = 0; jj < 8; ++jj)
#pragma unroll
            for (int q = 0; q < 4; ++q) acc[jj][q] = lb1[jj];
        mm_acc(acc, dWih, HH, h0s, rows, slb);
        mm_acc(acc, dWhh, HH, h1s, rows, slb);
        cell_upd(acc, c1r, h2);
        __syncthreads();
#pragma unroll
        for (int uu = 0; uu < 2; ++uu)
#pragma unroll
            for (int q = 0; q < 4; ++q) h1s[slb+q][u0+uu] = h2[uu][q];
        __syncthreads();  // MLP reads all of h1s

        // ---- MLP head ----
        float zacc[2][4];
#pragma unroll
        for (int uu = 0; uu < 2; ++uu) {
            const float* m = W1i + (u0+uu)*MPAD;
            float4 ma = *(const float4*)(m+0);
            float4 mbv = *(const float4*)(m+4);
            float4 mc = *(const float4*)(m+8);
            float4 md4 = *(const float4*)(m+12);
            float m16 = m[16], m17 = m[17];
#pragma unroll
            for (int q = 0; q < 4; ++q) {
                const float* ev = &envs[slb+q][0];
                float4 ea4 = *(const float4*)(ev+0);
                float4 eb4 = *(const float4*)(ev+4);
                float4 ec4 = *(const float4*)(ev+8);
                float4 ed4 = *(const float4*)(ev+12);
                float t0 = mb[uu][q];
                t0 = fmaf(ma.x, ea4.x, t0); t0 = fmaf(ma.y, ea4.y, t0);
                t0 = fmaf(ma.z, ea4.z, t0); t0 = fmaf(ma.w, ea4.w, t0);
                t0 = fmaf(mbv.x, eb4.x, t0); t0 = fmaf(mbv.y, eb4.y, t0);
                t0 = fmaf(mbv.z, eb4.z, t0); t0 = fmaf(mbv.w, eb4.w, t0);
                t0 = fmaf(mc.x, ec4.x, t0); t0 = fmaf(mc.y, ec4.y, t0);
                t0 = fmaf(mc.z, ec4.z, t0); t0 = fmaf(mc.w, ec4.w, t0);
                t0 = fmaf(md4.x, ed4.x, t0); t0 = fmaf(md4.y, ed4.y, t0);
                t0 = fmaf(md4.z, ed4.z, t0); t0 = fmaf(md4.w, ed4.w, t0);
                t0 = fmaf(m16, ev[16], t0);
                t0 = fmaf(m17, xv[q], t0);
                zacc[uu][q] = t0;
            }
        }
#pragma unroll 2
        for (int k4 = 0; k4 < 32; ++k4) {
            float4 hv[4];
#pragma unroll
            for (int q = 0; q < 4; ++q) hv[q] = *(const float4*)(&h1s[slb+q][k4*4]);
#pragma unroll
            for (int uu = 0; uu < 2; ++uu) {
                float4 w = *(const float4*)(W1h + (u0+uu)*HH + k4*4);
#pragma unroll
                for (int q = 0; q < 4; ++q)
                    zacc[uu][q] = fmaf(w.x, hv[q].x, fmaf(w.y, hv[q].y,
                                  fmaf(w.z, hv[q].z, fmaf(w.w, hv[q].w, zacc[uu][q]))));
            }
        }
#pragma unroll
        for (int uu = 0; uu < 2; ++uu)
#pragma unroll
            for (int q = 0; q < 4; ++q) {
                float z = zacc[uu][q];
                z = (z > 0.f) ? z : 0.01f*z;
                zms[slb+q][u0+uu] = z;
            }
        __syncthreads();

        if (tid < SAMP) {
            float a0 = mlp_b2[0], a1 = mlp_b2[1];
#pragma unroll 4
            for (int k4 = 0; k4 < 32; ++k4) {
                float4 z4 = *(const float4*)(&zms[tid][k4*4]);
                float4 w0 = *(const float4*)(mlp_W2 + k4*4);
                float4 w1 = *(const float4*)(mlp_W2 + HH + k4*4);
                a0 = fmaf(z4.x, w0.x, fmaf(z4.y, w0.y, fmaf(z4.z, w0.z, fmaf(z4.w, w0.w, a0))));
                a1 = fmaf(z4.x, w1.x, fmaf(z4.y, w1.y, fmaf(z4.z, w1.z, fmaf(z4.w, w1.w, a1))));
            }
            float xcv = xcs[tid];
            float xn = xcv + sigf(a0) - sigf(a1)*xcv;
            out[(size_t)(s0+tid)*HOR + td] = xn;
            xcs[tid] = xn;
        }
        __syncthreads();
    }
}

extern "C" void kernel_launch(void* const* d_in, const int* in_sizes, int n_in,
                              void* d_out, int out_size, void* d_ws, size_t ws_size,
                              hipStream_t stream)
{
    const float* x        = (const float*)d_in[0];
    const float* coords   = (const float*)d_in[1];
    const float* env      = (const float*)d_in[2];
    const float* areas    = (const float*)d_in[3];
    const float* W_enc_in = (const float*)d_in[4];
    const float* enc_Wih  = (const float*)d_in[5];
    const float* enc_Whh  = (const float*)d_in[6];
    const float* enc_bih  = (const float*)d_in[7];
    const float* enc_bhh  = (const float*)d_in[8];
    const float* W_dec_in = (const float*)d_in[9];
    const float* in_Wih   = (const float*)d_in[10];
    const float* in_Whh   = (const float*)d_in[11];
    const float* in_bih   = (const float*)d_in[12];
    const float* in_bhh   = (const float*)d_in[13];
    const float* dWih     = (const float*)d_in[14];
    const float* dWhh     = (const float*)d_in[15];
    const float* dbih     = (const float*)d_in[16];
    const float* dbhh     = (const float*)d_in[17];
    const float* mlp_W1   = (const float*)d_in[18];
    const float* mlp_b1   = (const float*)d_in[19];
    const float* mlp_W2   = (const float*)d_in[20];
    const float* mlp_b2   = (const float*)d_in[21];
    float* ws  = (float*)d_ws;
    float* out = (float*)d_out;

    fold_kernel<<<dim3(5), dim3(256), 0, stream>>>(enc_Wih, W_enc_in, in_Wih, W_dec_in, mlp_W1, ws);
    copyw1h_kernel<<<dim3(64), dim3(256), 0, stream>>>(mlp_W1, ws);
    lstm_main<<<dim3(NTOT/SAMP), dim3(256), 0, stream>>>(
        x, coords, env, areas, enc_Wih, enc_Whh, enc_bih, enc_bhh,
        in_Wih, in_Whh, in_bih, in_bhh, dWih, dWhh, dbih, dbhh,
        mlp_b1, mlp_W2, mlp_b2, ws, out);
}

// Round 2
// 1200.420 us; speedup vs baseline: 8.4069x; 8.4069x over previous
//
#include <hip/hip_runtime.h>

#define NTOT  10000
#define TALL  64
#define TCTX  24
#define HOR   40
#define HH    128
#define G4    512
#define NENV  17
#define SAMP  16

typedef __attribute__((ext_vector_type(8))) short  bf16x8;
typedef __attribute__((ext_vector_type(4))) float  f32x4;
typedef unsigned short u16;

// ---- ws fragment segments (units of 16-byte frags; ws byte offset = fid*16) ----
#define SEG_W0E   0
#define SEG_W0D   8192
#define SEG_WIH1  16384
#define SEG_WHH1  24576
#define SEG_DWIH  32768
#define SEG_DWHH  40960
#define SEG_M0E   49152
#define SEG_MDE   51200
#define SEG_WIHH  53248
#define SEG_W1H   61440
#define SEG_W1I   63488
#define NFRAGS    64000

// LDS layout (bytes)
#define L_WLDS  0
#define L_H0    131072
#define L_H1    135424
#define L_ZMS   139776
#define L_INPS  144128
#define L_XBLK  145408
#define L_W2L   146944
#define L_XCS   147968
#define SMEM_TOTAL 148032

__device__ __forceinline__ float sigf(float v)   { return 1.0f/(1.0f + __expf(-v)); }
__device__ __forceinline__ float tanhf_(float v) { return 1.0f - 2.0f/(__expf(2.0f*v) + 1.0f); }
__device__ __forceinline__ u16 f2bf(float f){
    unsigned int u = __float_as_uint(f);
    u += 0x7fffu + ((u >> 16) & 1u);
    return (u16)(u >> 16);
}
__device__ __forceinline__ float bf2f(u16 h){ return __uint_as_float(((unsigned int)h) << 16); }

// =====================  fold: build all bf16 fragment-packed weights  =====================
// inp32 column order: [0..16]=env, 17=x, 18=cd0, 19=cd1, 20=areas, 21=1(bias), 22..31=0
__global__ void fold_kernel(const float* __restrict__ enc_Wih, const float* __restrict__ enc_Whh,
                            const float* __restrict__ W_enc_in,
                            const float* __restrict__ in_Wih,  const float* __restrict__ in_Whh,
                            const float* __restrict__ W_dec_in,
                            const float* __restrict__ dWih,    const float* __restrict__ dWhh,
                            const float* __restrict__ mlp_W1,  const float* __restrict__ mlp_b1,
                            const float* __restrict__ enc_bih, const float* __restrict__ enc_bhh,
                            const float* __restrict__ in_bih,  const float* __restrict__ in_bhh,
                            void* __restrict__ ws)
{
    int fid = blockIdx.x*256 + threadIdx.x;
    if (fid >= NFRAGS) return;
    const int lane = fid & 63;
    const int cc = lane & 15;
    const int kg = lane >> 4;
    float vals[8];

    if (fid < 49152) {                       // six plain K=128 matrices
        int segi = fid >> 13;
        int loc  = fid & 8191;
        int gt   = loc >> 8;
        int kb   = (loc >> 6) & 3;
        int r    = gt*16 + cc;
        int k0   = kb*32 + kg*8;
        const float* src;
        switch (segi) {
            case 0: src = enc_Whh;          break;
            case 1: src = in_Whh;           break;
            case 2: src = enc_Wih + 65536;  break;
            case 3: src = enc_Whh + 65536;  break;
            case 4: src = dWih;             break;
            default: src = dWhh;            break;
        }
        #pragma unroll
        for (int j = 0; j < 8; ++j) vals[j] = src[(size_t)r*128 + k0 + j];
    } else if (fid < 53248) {                // M0E / MDE extended-input (K=32, folded chain)
        int loc = fid - 49152;
        int which = loc >> 11; loc &= 2047;
        int gt = loc >> 6;
        int r  = gt*16 + cc;
        int k0 = kg*8;
        const float* A = which ? (in_Wih + (size_t)r*256) : (enc_Wih + (size_t)r*128);
        const float* B = which ? W_dec_in : W_enc_in;
        float bias = which ? (in_bih[r] + in_bhh[r]) : (enc_bih[r] + enc_bhh[r]);
        #pragma unroll
        for (int j = 0; j < 8; ++j) {
            int k = k0 + j;
            float v = 0.f;
            int c = (k <= 16) ? (3 + k) : (k == 17 ? 0 : (k == 18 ? 1 : (k == 19 ? 2 : (k == 20 ? 20 : -1))));
            if (k == 21) v = bias;
            else if (c >= 0) {
                float a = 0.f;
                for (int h = 0; h < HH; ++h) a = fmaf(A[h], B[h*21 + c], a);
                v = a;
            }
            vals[j] = v;
        }
    } else if (fid < 61440) {                // WIHH = in_Wih[:,128:]
        int loc = fid - 53248;
        int gt = loc >> 8; int kb = (loc >> 6) & 3;
        int r = gt*16 + cc; int k0 = kb*32 + kg*8;
        #pragma unroll
        for (int j = 0; j < 8; ++j) vals[j] = in_Wih[(size_t)r*256 + 128 + k0 + j];
    } else if (fid < 63488) {                // W1H = mlp_W1[:,:128]
        int loc = fid - 61440;
        int gt = loc >> 8; int kb = (loc >> 6) & 3;
        int r = gt*16 + cc; int k0 = kb*32 + kg*8;
        #pragma unroll
        for (int j = 0; j < 8; ++j) vals[j] = mlp_W1[(size_t)r*149 + k0 + j];
    } else {                                  // W1I extended (mlp input part + b1)
        int loc = fid - 63488;
        int gt = loc >> 6;
        int r = gt*16 + cc; int k0 = kg*8;
        #pragma unroll
        for (int j = 0; j < 8; ++j) {
            int k = k0 + j; float v = 0.f;
            if (k <= 16)      v = mlp_W1[(size_t)r*149 + 131 + k];
            else if (k == 17) v = mlp_W1[(size_t)r*149 + 128];
            else if (k == 18) v = mlp_W1[(size_t)r*149 + 129];
            else if (k == 19) v = mlp_W1[(size_t)r*149 + 130];
            else if (k == 20) v = mlp_W1[(size_t)r*149 + 148];
            else if (k == 21) v = mlp_b1[r];
            vals[j] = v;
        }
    }
    union { uint4 u4; u16 us[8]; } pk;
    #pragma unroll
    for (int j = 0; j < 8; ++j) pk.us[j] = f2bf(vals[j]);
    *(uint4*)((char*)ws + (size_t)fid*16) = pk.u4;
}

// =====================  main persistent MFMA kernel  =====================
__global__ __launch_bounds__(256, 1)
void lstm_main(const float* __restrict__ x, const float* __restrict__ coords,
               const float* __restrict__ env, const float* __restrict__ areas,
               const float* __restrict__ enc_bih, const float* __restrict__ enc_bhh,
               const float* __restrict__ dbih,   const float* __restrict__ dbhh,
               const float* __restrict__ mlp_W2, const float* __restrict__ mlp_b2,
               const void* __restrict__ ws, float* __restrict__ out)
{
    extern __shared__ char smem[];
    u16*   WLDS = (u16*)(smem + L_WLDS);
    u16*   h0s  = (u16*)(smem + L_H0);
    u16*   h1s  = (u16*)(smem + L_H1);
    u16*   zms  = (u16*)(smem + L_ZMS);
    u16*   inps = (u16*)(smem + L_INPS);
    float* xblk = (float*)(smem + L_XBLK);
    float* w2l  = (float*)(smem + L_W2L);
    float* xcs  = (float*)(smem + L_XCS);

    const int tid  = threadIdx.x;
    const int lane = tid & 63;
    const int wid  = tid >> 6;
    const int cc   = lane & 15;
    const int kg   = lane >> 4;
    const int s0   = blockIdx.x * SAMP;
    const char* wsb = (const char*)ws;

    int gmap[8];
    #pragma unroll
    for (int m = 0; m < 8; ++m) gmap[m] = ((m >> 1) << 3) + (wid << 1) + (m & 1);

    // ---------------- init staging ----------------
    #pragma unroll 4
    for (int it = 0; it < 32; ++it) {
        int idx = it*256 + tid;
        ((uint4*)WLDS)[idx] = ((const uint4*)wsb)[idx];          // SEG_W0E at byte 0
    }
    for (int it = 0; it < 9; ++it) {
        int idx = it*256 + tid;
        if (idx < 2176) { h0s[idx] = 0; h1s[idx] = 0; }
    }
    #pragma unroll
    for (int rep = 0; rep < 2; ++rep) {
        int idx = rep*256 + tid;
        if (idx < 384) xblk[idx] = x[(size_t)(s0 + idx/24)*TALL + (idx % 24)];
    }
    w2l[tid] = mlp_W2[tid];

    const int sA = tid / NENV, eA = tid - sA*NENV;
    const int iB = tid + 256;
    const int sB = iB / NENV, eB = iB - sB*NENV;
    const float* envpA = env + ((size_t)(s0 + sA)*NENV + eA)*TALL;
    const float* envpB = env + ((size_t)(s0 + ((tid < 16) ? sB : 0))*NENV + ((tid < 16) ? eB : 0))*TALL;

    if (tid < SAMP) {
        inps[tid*40 + 18] = f2bf(coords[(size_t)(s0+tid)*2 + 0]);
        inps[tid*40 + 19] = f2bf(coords[(size_t)(s0+tid)*2 + 1]);
        inps[tid*40 + 20] = f2bf(areas[s0+tid]);
        inps[tid*40 + 21] = 0x3F80;   // bf16(1.0)
        #pragma unroll
        for (int c = 22; c < 32; ++c) inps[tid*40 + c] = 0;
    }

    // ---------------- encoder register weights ----------------
    bf16x8 WrA[32], WrB[32], MdB[8], W1HB[8], W1IB[2];
    float  lb1[8];
    #pragma unroll
    for (int m = 0; m < 8; ++m) {
        int gt = gmap[m];
        #pragma unroll
        for (int kb = 0; kb < 4; ++kb) {
            WrA[m*4+kb] = *(const bf16x8*)(wsb + ((size_t)(SEG_WIH1 + (gt*4+kb)*64 + lane))*16);
            WrB[m*4+kb] = *(const bf16x8*)(wsb + ((size_t)(SEG_WHH1 + (gt*4+kb)*64 + lane))*16);
        }
        MdB[m] = *(const bf16x8*)(wsb + ((size_t)(SEG_M0E + gt*64 + lane))*16);
        int grow = gt*16 + cc;
        lb1[m] = enc_bih[512 + grow] + enc_bhh[512 + grow];
    }

    float c0r[8], c1r[8];
    #pragma unroll
    for (int i = 0; i < 8; ++i) { c0r[i] = 0.f; c1r[i] = 0.f; }

    float evA = envpA[0];
    float evB = (tid < 16) ? envpB[0] : 0.f;
    __syncthreads();

    const f32x4 zero4 = {0.f, 0.f, 0.f, 0.f};

    // ================= encoder =================
    #pragma unroll 1
    for (int t = 0; t < TCTX; ++t) {
        inps[sA*40 + eA] = f2bf(evA);
        if (tid < 16) { inps[sB*40 + eB] = f2bf(evB); inps[tid*40 + 17] = f2bf(xblk[tid*24 + t]); }
        __syncthreads();                                   // bar1
        if (t + 1 < TALL) { evA = envpA[t+1]; if (tid < 16) evB = envpB[t+1]; }

        bf16x8 ia = *(const bf16x8*)(inps + cc*40 + kg*8);
        f32x4 acc[8];
        #pragma unroll
        for (int m = 0; m < 8; ++m)
            acc[m] = __builtin_amdgcn_mfma_f32_16x16x32_bf16(ia, MdB[m], zero4, 0, 0, 0);
        #pragma unroll
        for (int kb = 0; kb < 4; ++kb) {
            bf16x8 ha = *(const bf16x8*)(h0s + cc*136 + kb*32 + kg*8);
            #pragma unroll
            for (int m = 0; m < 8; ++m) {
                bf16x8 wb = *(const bf16x8*)((char*)WLDS + ((size_t)((gmap[m]*4+kb)*64 + lane))*16);
                acc[m] = __builtin_amdgcn_mfma_f32_16x16x32_bf16(ha, wb, acc[m], 0, 0, 0);
            }
        }
        float h2[8];
        #pragma unroll
        for (int ut = 0; ut < 2; ++ut)
        #pragma unroll
        for (int r = 0; r < 4; ++r) {
            float gi = acc[0+ut][r], gf = acc[2+ut][r], gg = acc[4+ut][r], go = acc[6+ut][r];
            float c2 = fmaf(sigf(gf), c0r[ut*4+r], sigf(gi)*tanhf_(gg));
            c0r[ut*4+r] = c2;
            h2[ut*4+r] = sigf(go)*tanhf_(c2);
        }
        __syncthreads();                                   // bar2
        #pragma unroll
        for (int ut = 0; ut < 2; ++ut)
        #pragma unroll
        for (int r = 0; r < 4; ++r)
            h0s[(kg*4+r)*136 + wid*32 + ut*16 + cc] = f2bf(h2[ut*4+r]);
        __syncthreads();                                   // bar3

        #pragma unroll
        for (int m = 0; m < 8; ++m) { f32x4 v = {lb1[m], lb1[m], lb1[m], lb1[m]}; acc[m] = v; }
        #pragma unroll
        for (int kb = 0; kb < 4; ++kb) {
            bf16x8 ha = *(const bf16x8*)(h0s + cc*136 + kb*32 + kg*8);
            #pragma unroll
            for (int m = 0; m < 8; ++m)
                acc[m] = __builtin_amdgcn_mfma_f32_16x16x32_bf16(ha, WrA[m*4+kb], acc[m], 0, 0, 0);
        }
        #pragma unroll
        for (int kb = 0; kb < 4; ++kb) {
            bf16x8 ha = *(const bf16x8*)(h1s + cc*136 + kb*32 + kg*8);
            #pragma unroll
            for (int m = 0; m < 8; ++m)
                acc[m] = __builtin_amdgcn_mfma_f32_16x16x32_bf16(ha, WrB[m*4+kb], acc[m], 0, 0, 0);
        }
        #pragma unroll
        for (int ut = 0; ut < 2; ++ut)
        #pragma unroll
        for (int r = 0; r < 4; ++r) {
            float gi = acc[0+ut][r], gf = acc[2+ut][r], gg = acc[4+ut][r], go = acc[6+ut][r];
            float c2 = fmaf(sigf(gf), c1r[ut*4+r], sigf(gi)*tanhf_(gg));
            c1r[ut*4+r] = c2;
            h2[ut*4+r] = sigf(go)*tanhf_(c2);
        }
        __syncthreads();                                   // bar4
        #pragma unroll
        for (int ut = 0; ut < 2; ++ut)
        #pragma unroll
        for (int r = 0; r < 4; ++r)
            h1s[(kg*4+r)*136 + wid*32 + ut*16 + cc] = f2bf(h2[ut*4+r]);
    }

    __syncthreads();   // enc_state final; all encoder WLDS reads done

    // ================= transition =================
    f32x4 baseD[8];
    #pragma unroll
    for (int m = 0; m < 8; ++m) baseD[m] = zero4;
    #pragma unroll
    for (int kb = 0; kb < 4; ++kb) {
        bf16x8 ha = *(const bf16x8*)(h1s + cc*136 + kb*32 + kg*8);
        #pragma unroll
        for (int m = 0; m < 8; ++m) {
            bf16x8 wb = *(const bf16x8*)(wsb + ((size_t)(SEG_WIHH + (gmap[m]*4+kb)*64 + lane))*16);
            baseD[m] = __builtin_amdgcn_mfma_f32_16x16x32_bf16(ha, wb, baseD[m], 0, 0, 0);
        }
    }
    #pragma unroll
    for (int m = 0; m < 8; ++m) {
        int gt = gmap[m];
        #pragma unroll
        for (int kb = 0; kb < 4; ++kb) {
            WrA[m*4+kb] = *(const bf16x8*)(wsb + ((size_t)(SEG_DWIH + (gt*4+kb)*64 + lane))*16);
            WrB[m*4+kb] = *(const bf16x8*)(wsb + ((size_t)(SEG_DWHH + (gt*4+kb)*64 + lane))*16);
        }
        MdB[m] = *(const bf16x8*)(wsb + ((size_t)(SEG_MDE + gt*64 + lane))*16);
        int grow = gt*16 + cc;
        lb1[m] = dbih[grow] + dbhh[grow];
    }
    #pragma unroll
    for (int uu = 0; uu < 2; ++uu) {
        int mt = (wid << 1) + uu;
        #pragma unroll
        for (int kb = 0; kb < 4; ++kb)
            W1HB[uu*4+kb] = *(const bf16x8*)(wsb + ((size_t)(SEG_W1H + (mt*4+kb)*64 + lane))*16);
        W1IB[uu] = *(const bf16x8*)(wsb + ((size_t)(SEG_W1I + mt*64 + lane))*16);
    }
    #pragma unroll 4
    for (int it = 0; it < 32; ++it) {
        int idx = it*256 + tid;
        ((uint4*)WLDS)[idx] = ((const uint4*)(wsb + (size_t)SEG_W0D*16))[idx];
    }
    if (tid < SAMP) {
        float xv = xblk[tid*24 + 23];
        xcs[tid] = xv;
        inps[tid*40 + 17] = f2bf(xv);
    }
    const float b20 = mlp_b2[0], b21 = mlp_b2[1];
    const int hs = lane >> 2, hq = lane & 3;
    __syncthreads();

    // ================= decoder =================
    #pragma unroll 1
    for (int td = 0; td < HOR; ++td) {
        const int t = TCTX + td;
        inps[sA*40 + eA] = f2bf(evA);
        if (tid < 16) inps[sB*40 + eB] = f2bf(evB);
        __syncthreads();                                   // bar1
        float xch = xcs[hs];
        if (t + 1 < TALL) { evA = envpA[t+1]; if (tid < 16) evB = envpB[t+1]; }

        bf16x8 ia = *(const bf16x8*)(inps + cc*40 + kg*8);
        f32x4 acc[8];
        #pragma unroll
        for (int m = 0; m < 8; ++m)
            acc[m] = __builtin_amdgcn_mfma_f32_16x16x32_bf16(ia, MdB[m], baseD[m], 0, 0, 0);
        #pragma unroll
        for (int kb = 0; kb < 4; ++kb) {
            bf16x8 ha = *(const bf16x8*)(h0s + cc*136 + kb*32 + kg*8);
            #pragma unroll
            for (int m = 0; m < 8; ++m) {
                bf16x8 wb = *(const bf16x8*)((char*)WLDS + ((size_t)((gmap[m]*4+kb)*64 + lane))*16);
                acc[m] = __builtin_amdgcn_mfma_f32_16x16x32_bf16(ha, wb, acc[m], 0, 0, 0);
            }
        }
        float h2[8];
        #pragma unroll
        for (int ut = 0; ut < 2; ++ut)
        #pragma unroll
        for (int r = 0; r < 4; ++r) {
            float gi = acc[0+ut][r], gf = acc[2+ut][r], gg = acc[4+ut][r], go = acc[6+ut][r];
            float c2 = fmaf(sigf(gf), c0r[ut*4+r], sigf(gi)*tanhf_(gg));
            c0r[ut*4+r] = c2;
            h2[ut*4+r] = sigf(go)*tanhf_(c2);
        }
        __syncthreads();                                   // bar2
        #pragma unroll
        for (int ut = 0; ut < 2; ++ut)
        #pragma unroll
        for (int r = 0; r < 4; ++r)
            h0s[(kg*4+r)*136 + wid*32 + ut*16 + cc] = f2bf(h2[ut*4+r]);
        __syncthreads();                                   // bar3

        #pragma unroll
        for (int m = 0; m < 8; ++m) { f32x4 v = {lb1[m], lb1[m], lb1[m], lb1[m]}; acc[m] = v; }
        #pragma unroll
        for (int kb = 0; kb < 4; ++kb) {
            bf16x8 ha = *(const bf16x8*)(h0s + cc*136 + kb*32 + kg*8);
            #pragma unroll
            for (int m = 0; m < 8; ++m)
                acc[m] = __builtin_amdgcn_mfma_f32_16x16x32_bf16(ha, WrA[m*4+kb], acc[m], 0, 0, 0);
        }
        #pragma unroll
        for (int kb = 0; kb < 4; ++kb) {
            bf16x8 ha = *(const bf16x8*)(h1s + cc*136 + kb*32 + kg*8);
            #pragma unroll
            for (int m = 0; m < 8; ++m)
                acc[m] = __builtin_amdgcn_mfma_f32_16x16x32_bf16(ha, WrB[m*4+kb], acc[m], 0, 0, 0);
        }
        #pragma unroll
        for (int ut = 0; ut < 2; ++ut)
        #pragma unroll
        for (int r = 0; r < 4; ++r) {
            float gi = acc[0+ut][r], gf = acc[2+ut][r], gg = acc[4+ut][r], go = acc[6+ut][r];
            float c2 = fmaf(sigf(gf), c1r[ut*4+r], sigf(gi)*tanhf_(gg));
            c1r[ut*4+r] = c2;
            h2[ut*4+r] = sigf(go)*tanhf_(c2);
        }
        __syncthreads();                                   // bar4
        #pragma unroll
        for (int ut = 0; ut < 2; ++ut)
        #pragma unroll
        for (int r = 0; r < 4; ++r)
            h1s[(kg*4+r)*136 + wid*32 + ut*16 + cc] = f2bf(h2[ut*4+r]);
        __syncthreads();                                   // bar5

        // ---- MLP ----
        f32x4 macc[2];
        #pragma unroll
        for (int uu = 0; uu < 2; ++uu)
            macc[uu] = __builtin_amdgcn_mfma_f32_16x16x32_bf16(ia, W1IB[uu], zero4, 0, 0, 0);
        #pragma unroll
        for (int kb = 0; kb < 4; ++kb) {
            bf16x8 ha = *(const bf16x8*)(h1s + cc*136 + kb*32 + kg*8);
            #pragma unroll
            for (int uu = 0; uu < 2; ++uu)
                macc[uu] = __builtin_amdgcn_mfma_f32_16x16x32_bf16(ha, W1HB[uu*4+kb], macc[uu], 0, 0, 0);
        }
        #pragma unroll
        for (int uu = 0; uu < 2; ++uu)
        #pragma unroll
        for (int r = 0; r < 4; ++r) {
            float z = macc[uu][r];
            z = (z > 0.f) ? z : 0.01f*z;
            zms[(kg*4+r)*136 + wid*32 + uu*16 + cc] = f2bf(z);
        }
        __syncthreads();                                   // bar6

        // ---- head (redundant per wave; wave0 lanes write) ----
        float a0 = 0.f, a1 = 0.f;
        #pragma unroll
        for (int c8 = 0; c8 < 4; ++c8) {
            bf16x8 z8 = *(const bf16x8*)(zms + hs*136 + hq*32 + c8*8);
            #pragma unroll
            for (int j = 0; j < 8; ++j) {
                float zf = bf2f((u16)z8[j]);
                int u = hq*32 + c8*8 + j;
                a0 = fmaf(zf, w2l[u], a0);
                a1 = fmaf(zf, w2l[128 + u], a1);
            }
        }
        a0 += __shfl_xor(a0, 1); a0 += __shfl_xor(a0, 2);
        a1 += __shfl_xor(a1, 1); a1 += __shfl_xor(a1, 2);
        float xn = xch + sigf(a0 + b20) - sigf(a1 + b21)*xch;
        if (wid == 0 && hq == 0) {
            xcs[hs] = xn;
            inps[hs*40 + 17] = f2bf(xn);
            out[(size_t)(s0 + hs)*HOR + td] = xn;
        }
    }
}

extern "C" void kernel_launch(void* const* d_in, const int* in_sizes, int n_in,
                              void* d_out, int out_size, void* d_ws, size_t ws_size,
                              hipStream_t stream)
{
    const float* x        = (const float*)d_in[0];
    const float* coords   = (const float*)d_in[1];
    const float* env      = (const float*)d_in[2];
    const float* areas    = (const float*)d_in[3];
    const float* W_enc_in = (const float*)d_in[4];
    const float* enc_Wih  = (const float*)d_in[5];
    const float* enc_Whh  = (const float*)d_in[6];
    const float* enc_bih  = (const float*)d_in[7];
    const float* enc_bhh  = (const float*)d_in[8];
    const float* W_dec_in = (const float*)d_in[9];
    const float* in_Wih   = (const float*)d_in[10];
    const float* in_Whh   = (const float*)d_in[11];
    const float* in_bih   = (const float*)d_in[12];
    const float* in_bhh   = (const float*)d_in[13];
    const float* dWih     = (const float*)d_in[14];
    const float* dWhh     = (const float*)d_in[15];
    const float* dbih     = (const float*)d_in[16];
    const float* dbhh     = (const float*)d_in[17];
    const float* mlp_W1   = (const float*)d_in[18];
    const float* mlp_b1   = (const float*)d_in[19];
    const float* mlp_W2   = (const float*)d_in[20];
    const float* mlp_b2   = (const float*)d_in[21];
    float* out = (float*)d_out;

    fold_kernel<<<dim3(250), dim3(256), 0, stream>>>(
        enc_Wih, enc_Whh, W_enc_in, in_Wih, in_Whh, W_dec_in,
        dWih, dWhh, mlp_W1, mlp_b1, enc_bih, enc_bhh, in_bih, in_bhh, d_ws);

    hipFuncSetAttribute((const void*)lstm_main,
                        hipFuncAttributeMaxDynamicSharedMemorySize, SMEM_TOTAL);
    lstm_main<<<dim3(NTOT/SAMP), dim3(256), SMEM_TOTAL, stream>>>(
        x, coords, env, areas, enc_bih, enc_bhh, dbih, dbhh, mlp_W2, mlp_b2, d_ws, out);
    (void)in_sizes; (void)n_in; (void)out_size; (void)ws_size;
}

// Round 3
// 1009.118 us; speedup vs baseline: 10.0006x; 1.1896x over previous
//
#include <hip/hip_runtime.h>

#define NTOT  10000
#define TALL  64
#define TCTX  24
#define HOR   40
#define HH    128
#define G4    512
#define NENV  17
#define SAMP  16

typedef __attribute__((ext_vector_type(8))) short  bf16x8;
typedef __attribute__((ext_vector_type(4))) float  f32x4;
typedef unsigned short u16;

// ---- ws fragment segments (units of 16-byte frags; ws byte offset = fid*16) ----
#define SEG_W0E   0        // enc_Whh layer0
#define SEG_W0D   8192     // in_Whh
#define SEG_WIH1  16384    // enc_Wih layer1
#define SEG_WHH1  24576    // enc_Whh layer1
#define SEG_DWIH  32768    // dWih
#define SEG_DWHH  40960    // dWhh
#define SEG_M0E   49152    // M0-extended (K=32)
#define SEG_MDE   51200    // Md-extended
#define SEG_WIHH  53248    // in_Wih[:,128:]
#define SEG_W1H   61440    // mlp_W1[:,:128]
#define SEG_W1I   63488    // W1-extended (K=32)
#define NFRAGS    64000

// LDS layout (bytes)
#define L_MDL   0          // 32768 : M0E/MDE frags
#define L_W1H   32768      // 32768
#define L_W1I   65536      // 8192
#define L_BASE  73728      // 32768 : baseD f32
#define L_H0    106496     // 2 x 4352 (double-buffered)
#define L_H1    115200     // 2 x 4352
#define L_ZMS   123904     // 4352
#define L_INPS  128256     // 1280 : 16 x 40 u16
#define L_XBLK  129536     // 1536 : 16 x 24 f32
#define L_W2L   131072     // 1024 : 256 f32
#define L_XCS   132096     // 64
#define SMEM_TOTAL 132160

__device__ __forceinline__ float sigf(float v)   { return 1.0f/(1.0f + __expf(-v)); }
__device__ __forceinline__ float tanhf_(float v) { return 1.0f - 2.0f/(__expf(2.0f*v) + 1.0f); }
__device__ __forceinline__ u16 f2bf(float f){
    unsigned int u = __float_as_uint(f);
    u += 0x7fffu + ((u >> 16) & 1u);
    return (u16)(u >> 16);
}
__device__ __forceinline__ float bf2f(u16 h){ return __uint_as_float(((unsigned int)h) << 16); }

// =====================  fold: build all bf16 fragment-packed weights  =====================
// inp32 column order: [0..16]=env, 17=x, 18=cd0, 19=cd1, 20=areas, 21=1(bias), 22..31=0
__global__ void fold_kernel(const float* __restrict__ enc_Wih, const float* __restrict__ enc_Whh,
                            const float* __restrict__ W_enc_in,
                            const float* __restrict__ in_Wih,  const float* __restrict__ in_Whh,
                            const float* __restrict__ W_dec_in,
                            const float* __restrict__ dWih,    const float* __restrict__ dWhh,
                            const float* __restrict__ mlp_W1,  const float* __restrict__ mlp_b1,
                            const float* __restrict__ enc_bih, const float* __restrict__ enc_bhh,
                            const float* __restrict__ in_bih,  const float* __restrict__ in_bhh,
                            void* __restrict__ ws)
{
    int fid = blockIdx.x*256 + threadIdx.x;
    if (fid >= NFRAGS) return;
    const int lane = fid & 63;
    const int cc = lane & 15;
    const int kg = lane >> 4;
    float vals[8];

    if (fid < 49152) {                       // six plain K=128 matrices
        int segi = fid >> 13;
        int loc  = fid & 8191;
        int gt   = loc >> 8;
        int kb   = (loc >> 6) & 3;
        int r    = gt*16 + cc;
        int k0   = kb*32 + kg*8;
        const float* src;
        switch (segi) {
            case 0: src = enc_Whh;          break;
            case 1: src = in_Whh;           break;
            case 2: src = enc_Wih + 65536;  break;
            case 3: src = enc_Whh + 65536;  break;
            case 4: src = dWih;             break;
            default: src = dWhh;            break;
        }
        #pragma unroll
        for (int j = 0; j < 8; ++j) vals[j] = src[(size_t)r*128 + k0 + j];
    } else if (fid < 53248) {                // M0E / MDE extended-input (K=32, folded chain)
        int loc = fid - 49152;
        int which = loc >> 11; loc &= 2047;
        int gt = loc >> 6;
        int r  = gt*16 + cc;
        int k0 = kg*8;
        const float* A = which ? (in_Wih + (size_t)r*256) : (enc_Wih + (size_t)r*128);
        const float* B = which ? W_dec_in : W_enc_in;
        float bias = which ? (in_bih[r] + in_bhh[r]) : (enc_bih[r] + enc_bhh[r]);
        #pragma unroll
        for (int j = 0; j < 8; ++j) {
            int k = k0 + j;
            float v = 0.f;
            int c = (k <= 16) ? (3 + k) : (k == 17 ? 0 : (k == 18 ? 1 : (k == 19 ? 2 : (k == 20 ? 20 : -1))));
            if (k == 21) v = bias;
            else if (c >= 0) {
                float a = 0.f;
                for (int h = 0; h < HH; ++h) a = fmaf(A[h], B[h*21 + c], a);
                v = a;
            }
            vals[j] = v;
        }
    } else if (fid < 61440) {                // WIHH = in_Wih[:,128:]
        int loc = fid - 53248;
        int gt = loc >> 8; int kb = (loc >> 6) & 3;
        int r = gt*16 + cc; int k0 = kb*32 + kg*8;
        #pragma unroll
        for (int j = 0; j < 8; ++j) vals[j] = in_Wih[(size_t)r*256 + 128 + k0 + j];
    } else if (fid < 63488) {                // W1H = mlp_W1[:,:128]
        int loc = fid - 61440;
        int gt = loc >> 8; int kb = (loc >> 6) & 3;
        int r = gt*16 + cc; int k0 = kb*32 + kg*8;
        #pragma unroll
        for (int j = 0; j < 8; ++j) vals[j] = mlp_W1[(size_t)r*149 + k0 + j];
    } else {                                  // W1I extended (mlp input part + b1)
        int loc = fid - 63488;
        int gt = loc >> 6;
        int r = gt*16 + cc; int k0 = kg*8;
        #pragma unroll
        for (int j = 0; j < 8; ++j) {
            int k = k0 + j; float v = 0.f;
            if (k <= 16)      v = mlp_W1[(size_t)r*149 + 131 + k];
            else if (k == 17) v = mlp_W1[(size_t)r*149 + 128];
            else if (k == 18) v = mlp_W1[(size_t)r*149 + 129];
            else if (k == 19) v = mlp_W1[(size_t)r*149 + 130];
            else if (k == 20) v = mlp_W1[(size_t)r*149 + 148];
            else if (k == 21) v = mlp_b1[r];
            vals[j] = v;
        }
    }
    union { uint4 u4; u16 us[8]; } pk;
    #pragma unroll
    for (int j = 0; j < 8; ++j) pk.us[j] = f2bf(vals[j]);
    *(uint4*)((char*)ws + (size_t)fid*16) = pk.u4;
}

// =====================  main persistent MFMA kernel: 8 waves, reg-resident weights  ==========
__global__ __launch_bounds__(512, 2)
void lstm_main(const float* __restrict__ x, const float* __restrict__ coords,
               const float* __restrict__ env, const float* __restrict__ areas,
               const float* __restrict__ enc_bih, const float* __restrict__ enc_bhh,
               const float* __restrict__ dbih,   const float* __restrict__ dbhh,
               const float* __restrict__ mlp_W2, const float* __restrict__ mlp_b2,
               const void* __restrict__ ws, float* __restrict__ out)
{
    extern __shared__ char smem[];
    u16*   MdL  = (u16*)(smem + L_MDL);
    u16*   W1Hl = (u16*)(smem + L_W1H);
    u16*   W1Il = (u16*)(smem + L_W1I);
    float* baseL= (float*)(smem + L_BASE);
    u16*   zms  = (u16*)(smem + L_ZMS);
    u16*   inps = (u16*)(smem + L_INPS);
    float* xblk = (float*)(smem + L_XBLK);
    float* w2l  = (float*)(smem + L_W2L);
    float* xcs  = (float*)(smem + L_XCS);

    const int tid  = threadIdx.x;
    const int lane = tid & 63;
    const int wid  = tid >> 6;          // 0..7: unit block (units wid*16..wid*16+15)
    const int cc   = lane & 15;
    const int kg   = lane >> 4;
    const int s0   = blockIdx.x * SAMP;
    const char* wsb = (const char*)ws;
    const f32x4 zero4 = {0.f, 0.f, 0.f, 0.f};

    // ---------------- init LDS staging ----------------
    #pragma unroll
    for (int i = 0; i < 4; ++i) {
        ((uint4*)(smem + L_MDL))[i*512 + tid] = ((const uint4*)wsb)[SEG_M0E + i*512 + tid];
        ((uint4*)(smem + L_W1H))[i*512 + tid] = ((const uint4*)wsb)[SEG_W1H + i*512 + tid];
    }
    ((uint4*)(smem + L_W1I))[tid] = ((const uint4*)wsb)[SEG_W1I + tid];
    for (int i = tid; i < 2176; i += 512) {            // zero h buffers parity-1
        ((u16*)(smem + L_H0 + 4352))[i] = 0;
        ((u16*)(smem + L_H1 + 4352))[i] = 0;
    }
    if (tid < 384) xblk[tid] = x[(size_t)(s0 + tid/24)*TALL + (tid % 24)];
    if (tid < 256) w2l[tid] = mlp_W2[tid];
    if (tid < SAMP) {
        inps[tid*40 + 18] = f2bf(coords[(size_t)(s0+tid)*2 + 0]);
        inps[tid*40 + 19] = f2bf(coords[(size_t)(s0+tid)*2 + 1]);
        inps[tid*40 + 20] = f2bf(areas[s0+tid]);
        inps[tid*40 + 21] = 0x3F80;   // bf16(1.0) -> bias column
        #pragma unroll
        for (int c = 22; c < 32; ++c) inps[tid*40 + c] = 0;
    }

    // env staging: threads 0..271 each own one (sample, env-ch)
    const int sA = tid / NENV, eA = tid - sA*NENV;
    const bool envth = (tid < 272);
    const float* envp = env + ((size_t)(s0 + (envth ? sA : 0))*NENV + (envth ? eA : 0))*TALL;
    float evA = envth ? envp[0] : 0.f;

    // ---------------- register weights (48 frags = 192 VGPR) ----------------
    bf16x8 W0r[16], WrA[16], WrB[16];
    float  lb1[4];
    #pragma unroll
    for (int g = 0; g < 4; ++g) {
        int gt = g*8 + wid;
        #pragma unroll
        for (int kb = 0; kb < 4; ++kb) {
            W0r[g*4+kb] = *(const bf16x8*)(wsb + ((size_t)(SEG_W0E  + (gt*4+kb)*64 + lane))*16);
            WrA[g*4+kb] = *(const bf16x8*)(wsb + ((size_t)(SEG_WIH1 + (gt*4+kb)*64 + lane))*16);
            WrB[g*4+kb] = *(const bf16x8*)(wsb + ((size_t)(SEG_WHH1 + (gt*4+kb)*64 + lane))*16);
        }
        int grow = gt*16 + cc;
        lb1[g] = enc_bih[512 + grow] + enc_bhh[512 + grow];
    }

    float c0r[4] = {0.f,0.f,0.f,0.f};
    float c1r[4] = {0.f,0.f,0.f,0.f};
    __syncthreads();

    // ================= encoder: 2 barriers/step =================
    #pragma unroll 1
    for (int t = 0; t < TCTX; ++t) {
        u16* h0w = (u16*)(smem + L_H0 + (t&1)*4352);
        u16* h0r = (u16*)(smem + L_H0 + ((t&1)^1)*4352);
        u16* h1w = (u16*)(smem + L_H1 + (t&1)*4352);
        u16* h1r = (u16*)(smem + L_H1 + ((t&1)^1)*4352);

        if (envth)    inps[sA*40 + eA]  = f2bf(evA);
        if (tid < 16) inps[tid*40 + 17] = f2bf(xblk[tid*24 + t]);
        __syncthreads();                                   // bar_inps
        if (envth && t+1 < TALL) evA = envp[t+1];

        bf16x8 ia = *(const bf16x8*)(inps + cc*40 + kg*8);
        f32x4 acc[4];
        #pragma unroll
        for (int g = 0; g < 4; ++g) {
            bf16x8 md = *(const bf16x8*)(MdL + ((size_t)((g*8+wid)*64 + lane))*8);
            acc[g] = __builtin_amdgcn_mfma_f32_16x16x32_bf16(ia, md, zero4, 0, 0, 0);
        }
        #pragma unroll
        for (int kb = 0; kb < 4; ++kb) {
            bf16x8 ha = *(const bf16x8*)(h0r + cc*136 + kb*32 + kg*8);
            #pragma unroll
            for (int g = 0; g < 4; ++g)
                acc[g] = __builtin_amdgcn_mfma_f32_16x16x32_bf16(ha, W0r[g*4+kb], acc[g], 0, 0, 0);
        }
        float h2[4];
        #pragma unroll
        for (int r = 0; r < 4; ++r) {
            float c2 = fmaf(sigf(acc[1][r]), c0r[r], sigf(acc[0][r])*tanhf_(acc[2][r]));
            c0r[r] = c2;
            h2[r] = sigf(acc[3][r])*tanhf_(c2);
        }
        #pragma unroll
        for (int r = 0; r < 4; ++r)
            h0w[(kg*4+r)*136 + wid*16 + cc] = f2bf(h2[r]);
        __syncthreads();                                   // bar_h0

        #pragma unroll
        for (int g = 0; g < 4; ++g) { f32x4 v = {lb1[g],lb1[g],lb1[g],lb1[g]}; acc[g] = v; }
        #pragma unroll
        for (int kb = 0; kb < 4; ++kb) {
            bf16x8 ha = *(const bf16x8*)(h0w + cc*136 + kb*32 + kg*8);
            #pragma unroll
            for (int g = 0; g < 4; ++g)
                acc[g] = __builtin_amdgcn_mfma_f32_16x16x32_bf16(ha, WrA[g*4+kb], acc[g], 0, 0, 0);
        }
        #pragma unroll
        for (int kb = 0; kb < 4; ++kb) {
            bf16x8 ha = *(const bf16x8*)(h1r + cc*136 + kb*32 + kg*8);
            #pragma unroll
            for (int g = 0; g < 4; ++g)
                acc[g] = __builtin_amdgcn_mfma_f32_16x16x32_bf16(ha, WrB[g*4+kb], acc[g], 0, 0, 0);
        }
        #pragma unroll
        for (int r = 0; r < 4; ++r) {
            float c2 = fmaf(sigf(acc[1][r]), c1r[r], sigf(acc[0][r])*tanhf_(acc[2][r]));
            c1r[r] = c2;
            h2[r] = sigf(acc[3][r])*tanhf_(c2);
        }
        #pragma unroll
        for (int r = 0; r < 4; ++r)
            h1w[(kg*4+r)*136 + wid*16 + cc] = f2bf(h2[r]);
        // no barrier: next bar_inps + bar_h0 cover publish before first read
    }

    __syncthreads();                                       // bar_T1: encoder state final

    // ================= transition =================
    {
        u16* hEnc = (u16*)(smem + L_H1 + 4352);            // h1 parity-1 = enc_state (t=23)
        f32x4 bD[4];
        #pragma unroll
        for (int g = 0; g < 4; ++g) bD[g] = zero4;
        #pragma unroll
        for (int kb = 0; kb < 4; ++kb) {
            bf16x8 ha = *(const bf16x8*)(hEnc + cc*136 + kb*32 + kg*8);
            #pragma unroll
            for (int g = 0; g < 4; ++g) {
                bf16x8 wb = *(const bf16x8*)(wsb + ((size_t)(SEG_WIHH + ((g*8+wid)*4+kb)*64 + lane))*16);
                bD[g] = __builtin_amdgcn_mfma_f32_16x16x32_bf16(ha, wb, bD[g], 0, 0, 0);
            }
        }
        #pragma unroll
        for (int g = 0; g < 4; ++g)
            *(f32x4*)(baseL + ((size_t)((wid*4+g)*64 + lane))*4) = bD[g];
    }
    #pragma unroll
    for (int g = 0; g < 4; ++g) {
        int gt = g*8 + wid;
        #pragma unroll
        for (int kb = 0; kb < 4; ++kb) {
            W0r[g*4+kb] = *(const bf16x8*)(wsb + ((size_t)(SEG_W0D  + (gt*4+kb)*64 + lane))*16);
            WrA[g*4+kb] = *(const bf16x8*)(wsb + ((size_t)(SEG_DWIH + (gt*4+kb)*64 + lane))*16);
            WrB[g*4+kb] = *(const bf16x8*)(wsb + ((size_t)(SEG_DWHH + (gt*4+kb)*64 + lane))*16);
        }
        int grow = gt*16 + cc;
        lb1[g] = dbih[grow] + dbhh[grow];
    }
    #pragma unroll
    for (int i = 0; i < 4; ++i)
        ((uint4*)(smem + L_MDL))[i*512 + tid] = ((const uint4*)wsb)[SEG_MDE + i*512 + tid];
    if (tid < SAMP) {
        float xv = xblk[tid*24 + 23];
        xcs[tid] = xv;
        inps[tid*40 + 17] = f2bf(xv);
    }
    const float b20 = mlp_b2[0], b21 = mlp_b2[1];
    const int hs = lane >> 2, hq = lane & 3;
    __syncthreads();                                       // bar_T2

    // ================= decoder: 4 barriers/step =================
    #pragma unroll 1
    for (int td = 0; td < HOR; ++td) {
        const int q = td & 1;                              // td=0 reads parity-1 (enc state)
        u16* h0w = (u16*)(smem + L_H0 + q*4352);
        u16* h0r = (u16*)(smem + L_H0 + (q^1)*4352);
        u16* h1w = (u16*)(smem + L_H1 + q*4352);
        u16* h1r = (u16*)(smem + L_H1 + (q^1)*4352);

        if (envth) inps[sA*40 + eA] = f2bf(evA);
        __syncthreads();                                   // bar_inps
        if (envth && TCTX+td+1 < TALL) evA = envp[TCTX+td+1];

        bf16x8 ia = *(const bf16x8*)(inps + cc*40 + kg*8);
        f32x4 acc[4];
        #pragma unroll
        for (int g = 0; g < 4; ++g) {
            f32x4 cb = *(const f32x4*)(baseL + ((size_t)((wid*4+g)*64 + lane))*4);
            bf16x8 md = *(const bf16x8*)(MdL + ((size_t)((g*8+wid)*64 + lane))*8);
            acc[g] = __builtin_amdgcn_mfma_f32_16x16x32_bf16(ia, md, cb, 0, 0, 0);
        }
        #pragma unroll
        for (int kb = 0; kb < 4; ++kb) {
            bf16x8 ha = *(const bf16x8*)(h0r + cc*136 + kb*32 + kg*8);
            #pragma unroll
            for (int g = 0; g < 4; ++g)
                acc[g] = __builtin_amdgcn_mfma_f32_16x16x32_bf16(ha, W0r[g*4+kb], acc[g], 0, 0, 0);
        }
        float h2[4];
        #pragma unroll
        for (int r = 0; r < 4; ++r) {
            float c2 = fmaf(sigf(acc[1][r]), c0r[r], sigf(acc[0][r])*tanhf_(acc[2][r]));
            c0r[r] = c2;
            h2[r] = sigf(acc[3][r])*tanhf_(c2);
        }
        #pragma unroll
        for (int r = 0; r < 4; ++r)
            h0w[(kg*4+r)*136 + wid*16 + cc] = f2bf(h2[r]);
        __syncthreads();                                   // bar_h0

        #pragma unroll
        for (int g = 0; g < 4; ++g) { f32x4 v = {lb1[g],lb1[g],lb1[g],lb1[g]}; acc[g] = v; }
        #pragma unroll
        for (int kb = 0; kb < 4; ++kb) {
            bf16x8 ha = *(const bf16x8*)(h0w + cc*136 + kb*32 + kg*8);
            #pragma unroll
            for (int g = 0; g < 4; ++g)
                acc[g] = __builtin_amdgcn_mfma_f32_16x16x32_bf16(ha, WrA[g*4+kb], acc[g], 0, 0, 0);
        }
        #pragma unroll
        for (int kb = 0; kb < 4; ++kb) {
            bf16x8 ha = *(const bf16x8*)(h1r + cc*136 + kb*32 + kg*8);
            #pragma unroll
            for (int g = 0; g < 4; ++g)
                acc[g] = __builtin_amdgcn_mfma_f32_16x16x32_bf16(ha, WrB[g*4+kb], acc[g], 0, 0, 0);
        }
        #pragma unroll
        for (int r = 0; r < 4; ++r) {
            float c2 = fmaf(sigf(acc[1][r]), c1r[r], sigf(acc[0][r])*tanhf_(acc[2][r]));
            c1r[r] = c2;
            h2[r] = sigf(acc[3][r])*tanhf_(c2);
        }
        #pragma unroll
        for (int r = 0; r < 4; ++r)
            h1w[(kg*4+r)*136 + wid*16 + cc] = f2bf(h2[r]);
        __syncthreads();                                   // bar_h1 (MLP consumes h1w)

        // ---- MLP (wave wid -> output units wid*16..+15) ----
        bf16x8 w1i = *(const bf16x8*)(W1Il + ((size_t)(wid*64 + lane))*8);
        f32x4 macc = __builtin_amdgcn_mfma_f32_16x16x32_bf16(ia, w1i, zero4, 0, 0, 0);
        #pragma unroll
        for (int kb = 0; kb < 4; ++kb) {
            bf16x8 ha = *(const bf16x8*)(h1w + cc*136 + kb*32 + kg*8);
            bf16x8 wb = *(const bf16x8*)(W1Hl + ((size_t)((wid*4+kb)*64 + lane))*8);
            macc = __builtin_amdgcn_mfma_f32_16x16x32_bf16(ha, wb, macc, 0, 0, 0);
        }
        #pragma unroll
        for (int r = 0; r < 4; ++r) {
            float z = macc[r];
            z = (z > 0.f) ? z : 0.01f*z;
            zms[(kg*4+r)*136 + wid*16 + cc] = f2bf(z);
        }
        __syncthreads();                                   // bar_z

        // ---- head: wave 0 only ----
        if (wid == 0) {
            float xch = xcs[hs];
            float a0 = 0.f, a1 = 0.f;
            #pragma unroll
            for (int c8 = 0; c8 < 4; ++c8) {
                bf16x8 z8 = *(const bf16x8*)(zms + hs*136 + hq*32 + c8*8);
                #pragma unroll
                for (int j = 0; j < 8; ++j) {
                    float zf = bf2f((u16)z8[j]);
                    int u = hq*32 + c8*8 + j;
                    a0 = fmaf(zf, w2l[u], a0);
                    a1 = fmaf(zf, w2l[128 + u], a1);
                }
            }
            a0 += __shfl_xor(a0, 1); a0 += __shfl_xor(a0, 2);
            a1 += __shfl_xor(a1, 1); a1 += __shfl_xor(a1, 2);
            float xn = xch + sigf(a0 + b20) - sigf(a1 + b21)*xch;
            if (hq == 0) {
                xcs[hs] = xn;
                inps[hs*40 + 17] = f2bf(xn);
                out[(size_t)(s0 + hs)*HOR + td] = xn;
            }
        }
        // next bar_inps publishes head's writes
    }
}

extern "C" void kernel_launch(void* const* d_in, const int* in_sizes, int n_in,
                              void* d_out, int out_size, void* d_ws, size_t ws_size,
                              hipStream_t stream)
{
    const float* x        = (const float*)d_in[0];
    const float* coords   = (const float*)d_in[1];
    const float* env      = (const float*)d_in[2];
    const float* areas    = (const float*)d_in[3];
    const float* W_enc_in = (const float*)d_in[4];
    const float* enc_Wih  = (const float*)d_in[5];
    const float* enc_Whh  = (const float*)d_in[6];
    const float* enc_bih  = (const float*)d_in[7];
    const float* enc_bhh  = (const float*)d_in[8];
    const float* W_dec_in = (const float*)d_in[9];
    const float* in_Wih   = (const float*)d_in[10];
    const float* in_Whh   = (const float*)d_in[11];
    const float* in_bih   = (const float*)d_in[12];
    const float* in_bhh   = (const float*)d_in[13];
    const float* dWih     = (const float*)d_in[14];
    const float* dWhh     = (const float*)d_in[15];
    const float* dbih     = (const float*)d_in[16];
    const float* dbhh     = (const float*)d_in[17];
    const float* mlp_W1   = (const float*)d_in[18];
    const float* mlp_b1   = (const float*)d_in[19];
    const float* mlp_W2   = (const float*)d_in[20];
    const float* mlp_b2   = (const float*)d_in[21];
    float* out = (float*)d_out;

    fold_kernel<<<dim3(250), dim3(256), 0, stream>>>(
        enc_Wih, enc_Whh, W_enc_in, in_Wih, in_Whh, W_dec_in,
        dWih, dWhh, mlp_W1, mlp_b1, enc_bih, enc_bhh, in_bih, in_bhh, d_ws);

    hipFuncSetAttribute((const void*)lstm_main,
                        hipFuncAttributeMaxDynamicSharedMemorySize, SMEM_TOTAL);
    lstm_main<<<dim3(NTOT/SAMP), dim3(512), SMEM_TOTAL, stream>>>(
        x, coords, env, areas, enc_bih, enc_bhh, dbih, dbhh, mlp_W2, mlp_b2, d_ws, out);
    (void)in_sizes; (void)n_in; (void)out_size; (void)ws_size;
}